// Round 1
// baseline (463.867 us; speedup 1.0000x reference)
//
#include <hip/hip_runtime.h>

#define NBINS 65536
#define NSHADOW 2
#define B 4
#define C 16
#define H 192
#define WD 192
#define HID 32
#define NI 32
#define INTER (H*WD)          // 36864 interior pixels per image
#define PADMULT 28672         // 256*256 - 192*192 padded pixels per channel
#define EPSF 1e-6f

// ws offsets in 4-byte units
#define OFF_COUNTS 0                      // [B][NI] float
#define OFF_CSUMS  (OFF_COUNTS + B*NI)    // [B][NI][C] float
#define OFF_V      (OFF_CSUMS + B*NI*C)   // [B][NI][HID] float
#define OFF_PERR   (OFF_V + B*NI*HID)     // [B][NI] float
#define OFF_MINK   (OFF_PERR + B*NI)      // [B] uint (mapped float, min)
#define OFF_MAXK   (OFF_MINK + B)         // [B] uint (mapped float, max)
#define OFF_HIST   8192                   // [B][NSHADOW][2][NBINS] uint
#define WS_UINTS   (OFF_HIST + B*NSHADOW*2*NBINS)

__device__ inline unsigned fmap(float f) {
    unsigned u = __float_as_uint(f);
    return (u & 0x80000000u) ? ~u : (u | 0x80000000u);
}
__device__ inline float funmap(unsigned k) {
    return (k & 0x80000000u) ? __uint_as_float(k & 0x7fffffffu)
                             : __uint_as_float(~k);
}

// Kernel 1: weighted per-instance counts and embedding sums (interior only;
// padding contributes zero because padded w == 0).
__global__ void k_counts(const float* emb, const float* wgt, const int* gt,
                         float* ws) {
    __shared__ float s_cnt[NI];
    __shared__ float s_sum[NI * C];
    int tid = threadIdx.x;
    int img = blockIdx.y;
    for (int i = tid; i < NI; i += 256) s_cnt[i] = 0.f;
    for (int i = tid; i < NI * C; i += 256) s_sum[i] = 0.f;
    __syncthreads();
    int p = blockIdx.x * 256 + tid;  // 144 blocks * 256 == 36864 exactly
    int g = gt[img * INTER + p];
    if (g > 0 && g <= NI) {
        float wv = wgt[img * INTER + p];
        atomicAdd(&s_cnt[g - 1], wv);
        const float* e = emb + (size_t)img * C * INTER + p;
        #pragma unroll
        for (int c = 0; c < C; c++)
            atomicAdd(&s_sum[(g - 1) * C + c], e[c * INTER] * wv);
    }
    __syncthreads();
    for (int i = tid; i < NI; i += 256)
        atomicAdd(&ws[OFF_COUNTS + img * NI + i], s_cnt[i]);
    for (int i = tid; i < NI * C; i += 256)
        atomicAdd(&ws[OFF_CSUMS + (img * NI) * C + i], s_sum[i]);
}

// Kernel 2: v[n,k] = sum_c centers[n,c]*W1[c,k] + b1[k]; pad-region error per
// instance (emb==0, label==0 there): perr[n] = 1 + sum_k relu(v[n,k])*W2[k] + b2.
__global__ void k_centers(const float* W1, const float* b1, const float* W2,
                          const float* b2, float* ws, unsigned* wsu) {
    int img = blockIdx.x;
    int tid = threadIdx.x;
    __shared__ float s_v[NI * HID];
    for (int idx = tid; idx < NI * HID; idx += 256) {
        int n = idx >> 5, k = idx & 31;
        float cnt = ws[OFF_COUNTS + img * NI + n] + EPSF;
        float acc = b1[k];
        #pragma unroll
        for (int c = 0; c < C; c++)
            acc += (ws[OFF_CSUMS + (img * NI + n) * C + c] / cnt) * W1[c * HID + k];
        s_v[idx] = acc;
        ws[OFF_V + (img * NI + n) * HID + k] = acc;
    }
    __syncthreads();
    if (tid < NI) {
        float lg = b2[0];
        #pragma unroll
        for (int k = 0; k < HID; k++)
            lg += fmaxf(s_v[tid * HID + k], 0.f) * W2[k];
        float pe = 1.f + lg;           // label = 0 in padding
        ws[OFF_PERR + img * NI + tid] = pe;
        unsigned key = fmap(pe);
        atomicMin(&wsu[OFF_MINK + img], key);
        atomicMax(&wsu[OFF_MAXK + img], key);
    }
}

// Kernel 3/4 (template): per interior pixel compute 32 channel errors.
// MODE 0: global min/max reduction.  MODE 1: histogram (count + positives).
template <int MODE>
__global__ void k_errs(const float* emb, const int* gt, const float* W1,
                       const float* W2, const float* b2, const float* ws,
                       unsigned* wsu) {
    int img = blockIdx.y;
    int tid = threadIdx.x;
    __shared__ float s_v[NI * HID];   // 4 KB
    __shared__ float s_w1[C * HID];   // 2 KB
    __shared__ float s_w2[HID];
    for (int i = tid; i < NI * HID; i += 256) s_v[i] = ws[OFF_V + img * NI * HID + i];
    for (int i = tid; i < C * HID; i += 256) s_w1[i] = W1[i];
    if (tid < HID) s_w2[tid] = W2[tid];
    __syncthreads();

    int p = blockIdx.x * 256 + tid;
    const float* ep = emb + (size_t)img * C * INTER + p;
    float u[HID];
    #pragma unroll
    for (int k = 0; k < HID; k++) u[k] = 0.f;
    #pragma unroll
    for (int c = 0; c < C; c++) {
        float ev = ep[c * INTER];
        #pragma unroll
        for (int k = 0; k < HID; k++) u[k] = fmaf(ev, s_w1[c * HID + k], u[k]);
    }
    int g = gt[img * INTER + p];
    float b2v = b2[0];

    float emax = 0.f, invbw = 0.f;
    unsigned* hist = nullptr;
    if constexpr (MODE == 1) {
        emax = funmap(wsu[OFF_MAXK + img]);
        float emin = funmap(wsu[OFF_MINK + img]);
        invbw = (float)NBINS / fmaxf(emax - emin, 1e-20f);
        hist = wsu + OFF_HIST + (size_t)(img * NSHADOW + (blockIdx.x & (NSHADOW - 1))) * 2 * NBINS;
    }

    float lmin = 1e30f, lmax = -1e30f;
    for (int n = 0; n < NI; n++) {
        float lg = b2v;
        #pragma unroll
        for (int k = 0; k < HID; k++)
            lg = fmaf(fmaxf(s_v[n * HID + k] - u[k], 0.f), s_w2[k], lg);
        bool pos = (g == n + 1);
        float err = pos ? (1.f - lg) : (1.f + lg);
        if constexpr (MODE == 0) {
            lmin = fminf(lmin, err);
            lmax = fmaxf(lmax, err);
        } else {
            int b = (int)((emax - err) * invbw);
            b = b < 0 ? 0 : (b >= NBINS ? NBINS - 1 : b);
            atomicAdd(&hist[b], 1u);
            if (pos) atomicAdd(&hist[NBINS + b], 1u);
        }
    }
    if constexpr (MODE == 0) {
        __shared__ unsigned bmin, bmax;
        if (tid == 0) { bmin = 0xFFFFFFFFu; bmax = 0u; }
        __syncthreads();
        atomicMin(&bmin, fmap(lmin));
        atomicMax(&bmax, fmap(lmax));
        __syncthreads();
        if (tid == 0) {
            atomicMin(&wsu[OFF_MINK + img], bmin);
            atomicMax(&wsu[OFF_MAXK + img], bmax);
        }
    }
}

// Pad-region histogram: each (img, n) pad error occurs PADMULT times, label 0.
__global__ void k_padhist(const float* ws, unsigned* wsu) {
    int img = blockIdx.x;
    int n = threadIdx.x;  // 32 threads
    float pe = ws[OFF_PERR + img * NI + n];
    float emax = funmap(wsu[OFF_MAXK + img]);
    float emin = funmap(wsu[OFF_MINK + img]);
    float invbw = (float)NBINS / fmaxf(emax - emin, 1e-20f);
    int b = (int)((emax - pe) * invbw);
    b = b < 0 ? 0 : (b >= NBINS ? NBINS - 1 : b);
    atomicAdd(&wsu[OFF_HIST + (size_t)img * NSHADOW * 2 * NBINS + b], (unsigned)PADMULT);
}

// Kernel 5: per-image scan over bins (descending error order) -> Lovasz loss.
// Contribution of a tied group at error e: relu(e) * (J(r2,L2) - J(r1,L1)),
// J(r,L) = 1 - (G-L)/(G+r-L).  Double precision kills cancellation.
__global__ void k_loss(const unsigned* wsu, float* out) {
    const int T = 1024;
    const int CHUNK = NBINS / T;  // 64
    int img = blockIdx.x, tid = threadIdx.x;
    const unsigned* h0 = wsu + OFF_HIST + (size_t)img * NSHADOW * 2 * NBINS;
    int base = tid * CHUNK;
    unsigned ccnt = 0, cpos = 0;
    for (int b = 0; b < CHUNK; b++) {
        int bi = base + b;
        ccnt += h0[bi] + h0[2 * NBINS + bi];
        cpos += h0[NBINS + bi] + h0[3 * NBINS + bi];
    }
    __shared__ unsigned s_c[T], s_p[T], s_ec[T], s_ep[T];
    __shared__ unsigned s_G;
    s_c[tid] = ccnt; s_p[tid] = cpos;
    __syncthreads();
    if (tid == 0) {
        unsigned rc = 0, rp = 0;
        for (int t = 0; t < T; t++) { s_ec[t] = rc; s_ep[t] = rp; rc += s_c[t]; rp += s_p[t]; }
        s_G = rp;
    }
    __syncthreads();
    double Gd = (double)s_G;
    float emax = funmap(wsu[OFF_MAXK + img]);
    float emin = funmap(wsu[OFF_MINK + img]);
    float bw = (emax - emin) / (float)NBINS;
    double r = (double)s_ec[tid], L = (double)s_ep[tid];
    double Jprev = 1.0 - (Gd - L) / (Gd + r - L);
    double acc = 0.0;
    for (int b = 0; b < CHUNK; b++) {
        int bi = base + b;
        unsigned cv = h0[bi] + h0[2 * NBINS + bi];
        unsigned pv = h0[NBINS + bi] + h0[3 * NBINS + bi];
        if (cv) {
            r += (double)cv; L += (double)pv;
            double J = 1.0 - (Gd - L) / (Gd + r - L);
            float e = emax - ((float)bi + 0.5f) * bw;  // bin-center representative
            acc += (double)fmaxf(e, 0.f) * (J - Jprev);
            Jprev = J;
        }
    }
    __shared__ double s_a[T];
    s_a[tid] = acc;
    __syncthreads();
    for (int s = T / 2; s > 0; s >>= 1) {
        if (tid < s) s_a[tid] += s_a[tid + s];
        __syncthreads();
    }
    if (tid == 0) atomicAdd(out, (float)(s_a[0] * 0.25));  // mean over B=4
}

extern "C" void kernel_launch(void* const* d_in, const int* in_sizes, int n_in,
                              void* d_out, int out_size, void* d_ws, size_t ws_size,
                              hipStream_t stream) {
    const float* emb = (const float*)d_in[0];
    const float* wgt = (const float*)d_in[1];
    const int*   gt  = (const int*)d_in[2];
    const float* W1  = (const float*)d_in[3];
    const float* b1  = (const float*)d_in[4];
    const float* W2  = (const float*)d_in[5];
    const float* b2  = (const float*)d_in[6];
    float* out = (float*)d_out;
    float* ws  = (float*)d_ws;
    unsigned* wsu = (unsigned*)d_ws;

    hipMemsetAsync(d_ws, 0, (size_t)WS_UINTS * 4, stream);
    hipMemsetAsync((char*)d_ws + (size_t)OFF_MINK * 4, 0xFF, B * 4, stream);  // min keys -> UINT_MAX
    hipMemsetAsync(d_out, 0, sizeof(float), stream);

    dim3 g1(INTER / 256, B);
    k_counts<<<g1, 256, 0, stream>>>(emb, wgt, gt, ws);
    k_centers<<<B, 256, 0, stream>>>(W1, b1, W2, b2, ws, wsu);
    k_errs<0><<<g1, 256, 0, stream>>>(emb, gt, W1, W2, b2, ws, wsu);
    k_padhist<<<B, NI, 0, stream>>>(ws, wsu);
    k_errs<1><<<g1, 256, 0, stream>>>(emb, gt, W1, W2, b2, ws, wsu);
    k_loss<<<B, 1024, 0, stream>>>(wsu, out);
}

// Round 2
// 260.910 us; speedup vs baseline: 1.7779x; 1.7779x over previous
//
#include <hip/hip_runtime.h>

#define NBINS 3072
#define HB 36          // histogram partial-blocks per image
#define B 4
#define C 16
#define H 192
#define WD 192
#define HID 32
#define NI 32
#define INTER (H*WD)          // 36864 interior pixels per image
#define PADMULT 28672         // 256*256 - 192*192 padded pixels per instance
#define EPSF 1e-6f

// ws offsets in 4-byte units
#define OFF_COUNTS 0                      // [B][NI] float
#define OFF_CSUMS  (OFF_COUNTS + B*NI)    // [B][NI][C] float
#define OFF_V      (OFF_CSUMS + B*NI*C)   // [B][NI][HID] float
#define OFF_PERR   (OFF_V + B*NI*HID)     // [B][NI] float
#define OFF_MINK   (OFF_PERR + B*NI)      // [B] uint (mapped float, min)
#define OFF_MAXK   (OFF_MINK + B)         // [B] uint (mapped float, max)
#define OFF_HCNT   8192                   // [B][HB][NBINS] uint packed cnt|pos<<16
#define OFF_HSUM   (OFF_HCNT + B*HB*NBINS) // [B][HB][NBINS] float sum(relu(err))
#define WS_UINTS   (OFF_HSUM + B*HB*NBINS)

__device__ inline unsigned fmap(float f) {
    unsigned u = __float_as_uint(f);
    return (u & 0x80000000u) ? ~u : (u | 0x80000000u);
}
__device__ inline float funmap(unsigned k) {
    return (k & 0x80000000u) ? __uint_as_float(k & 0x7fffffffu)
                             : __uint_as_float(~k);
}

// Kernel 1: weighted per-instance counts and embedding sums (interior only;
// padding contributes zero because padded w == 0).
__global__ void k_counts(const float* emb, const float* wgt, const int* gt,
                         float* ws) {
    __shared__ float s_cnt[NI];
    __shared__ float s_sum[NI * C];
    int tid = threadIdx.x;
    int img = blockIdx.y;
    for (int i = tid; i < NI; i += 256) s_cnt[i] = 0.f;
    for (int i = tid; i < NI * C; i += 256) s_sum[i] = 0.f;
    __syncthreads();
    int p = blockIdx.x * 256 + tid;  // 144 blocks * 256 == 36864 exactly
    int g = gt[img * INTER + p];
    if (g > 0 && g <= NI) {
        float wv = wgt[img * INTER + p];
        atomicAdd(&s_cnt[g - 1], wv);
        const float* e = emb + (size_t)img * C * INTER + p;
        #pragma unroll
        for (int c = 0; c < C; c++)
            atomicAdd(&s_sum[(g - 1) * C + c], e[c * INTER] * wv);
    }
    __syncthreads();
    for (int i = tid; i < NI; i += 256)
        atomicAdd(&ws[OFF_COUNTS + img * NI + i], s_cnt[i]);
    for (int i = tid; i < NI * C; i += 256)
        atomicAdd(&ws[OFF_CSUMS + (img * NI) * C + i], s_sum[i]);
}

// Kernel 2: v[n,k] = sum_c centers[n,c]*W1[c,k] + b1[k]; pad-region error per
// instance (emb==0, label==0 there): perr[n] = 1 + sum_k relu(v[n,k])*W2[k] + b2.
__global__ void k_centers(const float* W1, const float* b1, const float* W2,
                          const float* b2, float* ws, unsigned* wsu) {
    int img = blockIdx.x;
    int tid = threadIdx.x;
    __shared__ float s_v[NI * HID];
    for (int idx = tid; idx < NI * HID; idx += 256) {
        int n = idx >> 5, k = idx & 31;
        float cnt = ws[OFF_COUNTS + img * NI + n] + EPSF;
        float acc = b1[k];
        #pragma unroll
        for (int c = 0; c < C; c++)
            acc += (ws[OFF_CSUMS + (img * NI + n) * C + c] / cnt) * W1[c * HID + k];
        s_v[idx] = acc;
        ws[OFF_V + (img * NI + n) * HID + k] = acc;
    }
    __syncthreads();
    if (tid < NI) {
        float lg = b2[0];
        #pragma unroll
        for (int k = 0; k < HID; k++)
            lg += fmaxf(s_v[tid * HID + k], 0.f) * W2[k];
        float pe = 1.f + lg;           // label = 0 in padding
        ws[OFF_PERR + img * NI + tid] = pe;
        unsigned key = fmap(pe);
        atomicMin(&wsu[OFF_MINK + img], key);
        atomicMax(&wsu[OFF_MAXK + img], key);
    }
}

// Kernel 3: per interior pixel compute 32 channel errors, global min/max.
__global__ void k_minmax(const float* emb, const int* gt, const float* W1,
                         const float* W2, const float* b2, const float* ws,
                         unsigned* wsu) {
    int img = blockIdx.y;
    int tid = threadIdx.x;
    __shared__ float s_v[NI * HID];
    __shared__ float s_w1[C * HID];
    __shared__ float s_w2[HID];
    for (int i = tid; i < NI * HID; i += 256) s_v[i] = ws[OFF_V + img * NI * HID + i];
    for (int i = tid; i < C * HID; i += 256) s_w1[i] = W1[i];
    if (tid < HID) s_w2[tid] = W2[tid];
    __syncthreads();

    int p = blockIdx.x * 256 + tid;
    const float* ep = emb + (size_t)img * C * INTER + p;
    float u[HID];
    #pragma unroll
    for (int k = 0; k < HID; k++) u[k] = 0.f;
    #pragma unroll
    for (int c = 0; c < C; c++) {
        float ev = ep[c * INTER];
        #pragma unroll
        for (int k = 0; k < HID; k++) u[k] = fmaf(ev, s_w1[c * HID + k], u[k]);
    }
    int g = gt[img * INTER + p];
    float b2v = b2[0];

    float lmin = 1e30f, lmax = -1e30f;
    for (int n = 0; n < NI; n++) {
        float lg = b2v;
        #pragma unroll
        for (int k = 0; k < HID; k++)
            lg = fmaf(fmaxf(s_v[n * HID + k] - u[k], 0.f), s_w2[k], lg);
        float err = (g == n + 1) ? (1.f - lg) : (1.f + lg);
        lmin = fminf(lmin, err);
        lmax = fmaxf(lmax, err);
    }
    __shared__ unsigned bmin, bmax;
    if (tid == 0) { bmin = 0xFFFFFFFFu; bmax = 0u; }
    __syncthreads();
    atomicMin(&bmin, fmap(lmin));
    atomicMax(&bmax, fmap(lmax));
    __syncthreads();
    if (tid == 0) {
        atomicMin(&wsu[OFF_MINK + img], bmin);
        atomicMax(&wsu[OFF_MAXK + img], bmax);
    }
}

// Kernel 4: LDS-private histogram per block; flush with PLAIN stores to a
// per-block global region (no global atomics -- they are write-through at
// 32B/atomic on gfx950 and cost 150MB of HBM writes in round 1).
// Packed LDS bins: cnt in low16, pos in high16 (max 32768/bin per block).
// Also accumulates per-bin sum(relu(err)) so k_loss can use the exact
// within-bin mean as the group representative.
__global__ void k_hist(const float* emb, const int* gt, const float* W1,
                       const float* W2, const float* b2, const float* ws,
                       unsigned* wsu) {
    int img = blockIdx.y, bx = blockIdx.x, tid = threadIdx.x;
    __shared__ float s_v[NI * HID];   // 4 KB
    __shared__ float s_w1[C * HID];   // 2 KB
    __shared__ float s_w2[HID];
    __shared__ unsigned s_h[NBINS];   // 12 KB
    __shared__ float s_s[NBINS];      // 12 KB
    for (int i = tid; i < NI * HID; i += 256) s_v[i] = ws[OFF_V + img * NI * HID + i];
    for (int i = tid; i < C * HID; i += 256) s_w1[i] = W1[i];
    if (tid < HID) s_w2[tid] = W2[tid];
    for (int i = tid; i < NBINS; i += 256) { s_h[i] = 0u; s_s[i] = 0.f; }
    float emax = funmap(wsu[OFF_MAXK + img]);
    float emin = funmap(wsu[OFF_MINK + img]);
    float invbw = (float)NBINS / fmaxf(emax - emin, 1e-20f);
    float b2v = b2[0];
    __syncthreads();

    #pragma unroll
    for (int it = 0; it < 4; ++it) {
        int p = bx * 1024 + it * 256 + tid;
        const float* ep = emb + (size_t)img * C * INTER + p;
        float u[HID];
        #pragma unroll
        for (int k = 0; k < HID; k++) u[k] = 0.f;
        #pragma unroll
        for (int c = 0; c < C; c++) {
            float ev = ep[c * INTER];
            #pragma unroll
            for (int k = 0; k < HID; k++) u[k] = fmaf(ev, s_w1[c * HID + k], u[k]);
        }
        int g = gt[img * INTER + p];
        for (int n = 0; n < NI; n++) {
            float lg = b2v;
            #pragma unroll
            for (int k = 0; k < HID; k++)
                lg = fmaf(fmaxf(s_v[n * HID + k] - u[k], 0.f), s_w2[k], lg);
            bool pos = (g == n + 1);
            float err = pos ? (1.f - lg) : (1.f + lg);
            int bn = (int)((emax - err) * invbw);
            bn = bn < 0 ? 0 : (bn >= NBINS ? NBINS - 1 : bn);
            atomicAdd(&s_h[bn], pos ? 0x10001u : 1u);
            atomicAdd(&s_s[bn], fmaxf(err, 0.f));
        }
    }
    __syncthreads();
    unsigned* gc = wsu + OFF_HCNT + (size_t)(img * HB + bx) * NBINS;
    float* gs = (float*)wsu + OFF_HSUM + (size_t)(img * HB + bx) * NBINS;
    for (int i = tid; i < NBINS; i += 256) { gc[i] = s_h[i]; gs[i] = s_s[i]; }
}

// Kernel 5: per-image -- sum the HB partial histograms, add pad-region
// contributions, scan bins in descending-error order, Lovasz loss in double.
__global__ void k_loss(const float* ws, const unsigned* wsu, float* out) {
    const int T = 256;
    const int CHUNK = NBINS / T;  // 12
    int img = blockIdx.x, tid = threadIdx.x;
    __shared__ unsigned s_cnt[NBINS], s_pos[NBINS];  // 24 KB
    __shared__ float s_sum[NBINS];                   // 12 KB
    __shared__ unsigned s_pc[T], s_pp[T], s_ec[T], s_ep[T];
    __shared__ unsigned s_G;
    __shared__ double s_a[T];

    // 1) reduce HB partials (coalesced: bin = tid + i*256)
    for (int i = 0; i < CHUNK; i++) {
        int bn = tid + i * T;
        unsigned cnt = 0, pos = 0; float sm = 0.f;
        for (int r = 0; r < HB; r++) {
            unsigned pk = wsu[OFF_HCNT + (size_t)(img * HB + r) * NBINS + bn];
            cnt += pk & 0xFFFFu;
            pos += pk >> 16;
            sm += ws[OFF_HSUM + (size_t)(img * HB + r) * NBINS + bn];
        }
        s_cnt[bn] = cnt; s_pos[bn] = pos; s_sum[bn] = sm;
    }
    __syncthreads();

    // 2) pad-region contributions: each (img,n) pad error occurs PADMULT times
    float emax = funmap(wsu[OFF_MAXK + img]);
    float emin = funmap(wsu[OFF_MINK + img]);
    float invbw = (float)NBINS / fmaxf(emax - emin, 1e-20f);
    if (tid < NI) {
        float pe = ws[OFF_PERR + img * NI + tid];
        int bn = (int)((emax - pe) * invbw);
        bn = bn < 0 ? 0 : (bn >= NBINS ? NBINS - 1 : bn);
        atomicAdd(&s_cnt[bn], (unsigned)PADMULT);
        atomicAdd(&s_sum[bn], (float)PADMULT * fmaxf(pe, 0.f));
    }
    __syncthreads();

    // 3) prefix over per-thread chunks
    unsigned ccnt = 0, cpos = 0;
    for (int j = 0; j < CHUNK; j++) {
        int bn = tid * CHUNK + j;
        ccnt += s_cnt[bn]; cpos += s_pos[bn];
    }
    s_pc[tid] = ccnt; s_pp[tid] = cpos;
    __syncthreads();
    if (tid == 0) {
        unsigned rc = 0, rp = 0;
        for (int t = 0; t < T; t++) { s_ec[t] = rc; s_ep[t] = rp; rc += s_pc[t]; rp += s_pp[t]; }
        s_G = rp;
    }
    __syncthreads();

    // 4) scan: contribution of tied group = mean(relu(err)) * (J_after - J_before)
    double Gd = (double)s_G;
    double r = (double)s_ec[tid], L = (double)s_ep[tid];
    double Jprev = 1.0 - (Gd - L) / (Gd + r - L);
    double acc = 0.0;
    for (int j = 0; j < CHUNK; j++) {
        int bn = tid * CHUNK + j;
        unsigned cv = s_cnt[bn], pv = s_pos[bn];
        if (cv) {
            r += (double)cv; L += (double)pv;
            double J = 1.0 - (Gd - L) / (Gd + r - L);
            double mean = (double)s_sum[bn] / (double)cv;  // mean relu(err) in bin
            acc += mean * (J - Jprev);
            Jprev = J;
        }
    }
    s_a[tid] = acc;
    __syncthreads();
    for (int s = T / 2; s > 0; s >>= 1) {
        if (tid < s) s_a[tid] += s_a[tid + s];
        __syncthreads();
    }
    if (tid == 0) atomicAdd(out, (float)(s_a[0] * 0.25));  // mean over B=4
}

extern "C" void kernel_launch(void* const* d_in, const int* in_sizes, int n_in,
                              void* d_out, int out_size, void* d_ws, size_t ws_size,
                              hipStream_t stream) {
    const float* emb = (const float*)d_in[0];
    const float* wgt = (const float*)d_in[1];
    const int*   gt  = (const int*)d_in[2];
    const float* W1  = (const float*)d_in[3];
    const float* b1  = (const float*)d_in[4];
    const float* W2  = (const float*)d_in[5];
    const float* b2  = (const float*)d_in[6];
    float* out = (float*)d_out;
    float* ws  = (float*)d_ws;
    unsigned* wsu = (unsigned*)d_ws;

    // zero only the small control region; histogram partials are fully
    // overwritten by plain stores in k_hist.
    hipMemsetAsync(d_ws, 0, (size_t)(OFF_MAXK + B) * 4, stream);
    hipMemsetAsync((char*)d_ws + (size_t)OFF_MINK * 4, 0xFF, B * 4, stream);
    hipMemsetAsync(d_out, 0, sizeof(float), stream);

    dim3 g1(INTER / 256, B);
    k_counts<<<g1, 256, 0, stream>>>(emb, wgt, gt, ws);
    k_centers<<<B, 256, 0, stream>>>(W1, b1, W2, b2, ws, wsu);
    k_minmax<<<g1, 256, 0, stream>>>(emb, gt, W1, W2, b2, ws, wsu);
    dim3 g2(HB, B);
    k_hist<<<g2, 256, 0, stream>>>(emb, gt, W1, W2, b2, ws, wsu);
    k_loss<<<B, 256, 0, stream>>>(ws, wsu, out);
}